// Round 20
// baseline (366.463 us; speedup 1.0000x reference)
//
#include <hip/hip_runtime.h>
#include <hip/hip_bf16.h>

// MultiHeadCausalSelfAttention: B=2, N=4096, C=512, H=8, D=64, causal, fp32 in/out.
// Pipeline: cvt(fused) -> QKV GEMM (scatter Q,K,V frag layouts) -> attn(+merge) -> proj.
// R20: R19 (equal-length part-blocks, 1280 blocks, 5/CU) with the merge fixed:
// R19's merge wrote only 16 of 32 bf16 per thread (j<2); restored to j<4 (R14-proven).

typedef __attribute__((ext_vector_type(8))) short s16x8;    // 8 bf16 = MFMA A/B frag
typedef __attribute__((ext_vector_type(4))) float f32x4;    // 16x16 C/D frag
typedef __attribute__((ext_vector_type(16))) float f32x16;  // 32x32 C/D frag
typedef __attribute__((ext_vector_type(4))) unsigned u32x4;

#define QSCALE 0.18033688011112042f  // D^-0.5 * log2(e), folded into Q

__device__ __forceinline__ ushort f2bf(float f) {
  unsigned u = __float_as_uint(f);
  u = (u + 0x7FFFu + ((u >> 16) & 1u)) >> 16;  // RNE
  return (ushort)u;
}

__device__ __forceinline__ unsigned cvt_pk_bf16(float a, float b) {
  unsigned r;
  asm("v_cvt_pk_bf16_f32 %0, %1, %2" : "=v"(r) : "v"(a), "v"(b));
  return r;  // low16 = bf16(a), high16 = bf16(b)
}

__device__ __forceinline__ float bflo(unsigned u) { return __uint_as_float(u << 16); }
__device__ __forceinline__ float bfhi(unsigned u) { return __uint_as_float(u & 0xffff0000u); }

// One fused cvt for x (1048576 float4), w_qkv (196608), w_proj (65536).
__global__ __launch_bounds__(256) void cvt_all(const float* __restrict__ x,
                                               const float* __restrict__ wq,
                                               const float* __restrict__ wp,
                                               ushort* __restrict__ xb,
                                               ushort* __restrict__ wqb,
                                               ushort* __restrict__ wpb) {
  int i = blockIdx.x * 256 + threadIdx.x;
  const float* src;
  ushort* dst;
  int off;
  if (i < 1048576) {
    src = x; dst = xb; off = i;
  } else if (i < 1245184) {
    src = wq; dst = wqb; off = i - 1048576;
  } else {
    src = wp; dst = wpb; off = i - 1245184;
  }
  float4 v = reinterpret_cast<const float4*>(src)[off];
  ushort4 o;
  o.x = f2bf(v.x); o.y = f2bf(v.y); o.z = f2bf(v.z); o.w = f2bf(v.w);
  reinterpret_cast<ushort4*>(dst)[off] = o;
}

// C = A[M,512] @ W[Nout,512]^T, bf16 MFMA 16x16, 128x128 tile, 4 waves, BK=32, dbuf.
// EPI 0 scatter layouts (for 32x32 attn frags); EPI 1: fp32 out + bias.
template <int EPI>
__global__ __launch_bounds__(256) void gemm_bt(const ushort* __restrict__ A,
                                               const ushort* __restrict__ W,
                                               ushort* __restrict__ q_ws,
                                               ushort* __restrict__ k_ws,
                                               ushort* __restrict__ vt_ws,
                                               float* __restrict__ outf,
                                               const float* __restrict__ bias) {
  __shared__ ushort As[2][128 * 32];
  __shared__ ushort Bs[2][128 * 32];
  const int tid = threadIdx.x;
  const int lane = tid & 63, wv = tid >> 6;
  const int wm = wv >> 1, wn = wv & 1;
  const int l15 = lane & 15, g = lane >> 4;
  const int tm = blockIdx.y * 128, tn = blockIdx.x * 128;

  f32x4 acc[4][4] = {};

#define GSTAGE(BUF, K0)                                                                    \
  do {                                                                                     \
    _Pragma("unroll") for (int it = 0; it < 2; ++it) {                                     \
      int slot = it * 256 + tid;                                                           \
      int row = slot >> 2;                                                                 \
      int ch = (slot & 3) ^ ((row >> 1) & 3);                                              \
      const int sb = (it * 256 + wv * 64) * 8; /* wave-uniform LDS base (ushorts) */       \
      __builtin_amdgcn_global_load_lds(                                                    \
          (const __attribute__((address_space(1))) void*)(A + (size_t)(tm + row) * 512 +   \
                                                          (K0) + ch * 8),                  \
          (__attribute__((address_space(3))) void*)(&As[BUF][0] + sb), 16, 0, 0);          \
      __builtin_amdgcn_global_load_lds(                                                    \
          (const __attribute__((address_space(1))) void*)(W + (size_t)(tn + row) * 512 +   \
                                                          (K0) + ch * 8),                  \
          (__attribute__((address_space(3))) void*)(&Bs[BUF][0] + sb), 16, 0, 0);          \
    }                                                                                      \
  } while (0)

  GSTAGE(0, 0);
  __syncthreads();
  int cur = 0;
  for (int t = 0; t < 16; ++t) {
    if (t < 15) GSTAGE(cur ^ 1, (t + 1) * 32);
    s16x8 af[4], bfr[4];
#pragma unroll
    for (int i = 0; i < 4; ++i) {
      int Ra = wm * 64 + i * 16 + l15;
      af[i] = reinterpret_cast<const s16x8*>(&As[cur][0])[Ra * 4 + (g ^ ((Ra >> 1) & 3))];
      int Rb = wn * 64 + i * 16 + l15;
      bfr[i] = reinterpret_cast<const s16x8*>(&Bs[cur][0])[Rb * 4 + (g ^ ((Rb >> 1) & 3))];
    }
#pragma unroll
    for (int mi = 0; mi < 4; ++mi)
#pragma unroll
      for (int ni = 0; ni < 4; ++ni)
        acc[mi][ni] =
            __builtin_amdgcn_mfma_f32_16x16x32_bf16(af[mi], bfr[ni], acc[mi][ni], 0, 0, 0);
    __syncthreads();
    cur ^= 1;
  }
#undef GSTAGE

  // C/D (16x16): col = lane&15, row = (lane>>4)*4 + reg
  const int rowb = tm + wm * 64 + g * 4;
  const int colb = tn + wn * 64 + l15;
#pragma unroll
  for (int mi = 0; mi < 4; ++mi) {
#pragma unroll
    for (int ni = 0; ni < 4; ++ni) {
      int r0 = rowb + mi * 16;
      int col = colb + ni * 16;
      if (EPI == 0) {
        int i3 = col >> 9, h = (col >> 6) & 7, d = col & 63;
        int b = r0 >> 12;
        int bh = b * 8 + h;
        if (i3 == 2) {  // V: 4 consecutive keys -> ushort4
          int n0 = r0 & 4095;
          int kt64 = n0 >> 6, key64 = n0 & 63;
          int kc = key64 >> 4, hk = (key64 >> 3) & 1, j0 = key64 & 7;
          int db = d >> 5, d31 = d & 31;
          ushort4 pk;
          pk.x = f2bf(acc[mi][ni][0]);
          pk.y = f2bf(acc[mi][ni][1]);
          pk.z = f2bf(acc[mi][ni][2]);
          pk.w = f2bf(acc[mi][ni][3]);
          *reinterpret_cast<ushort4*>(vt_ws + (size_t)(bh * 64 + kt64) * 4096 +
                                      ((db * 4 + kc) * 64 + d31 + 32 * hk) * 8 + j0) = pk;
        } else if (i3 == 1) {  // K: scalar x4
          int dt = d >> 4, hd = (d >> 3) & 1, j = d & 7;
#pragma unroll
          for (int r = 0; r < 4; ++r) {
            int n = (r0 + r) & 4095;
            int kt64 = n >> 6, key64 = n & 63;
            int kb = key64 >> 5, key31 = key64 & 31;
            k_ws[(size_t)(bh * 64 + kt64) * 4096 +
                 ((kb * 4 + dt) * 64 + key31 + 32 * hd) * 8 + j] = f2bf(acc[mi][ni][r]);
          }
        } else {  // Q: scalar x4, scaled
          int dt = d >> 4, hd = (d >> 3) & 1, j = d & 7;
#pragma unroll
          for (int r = 0; r < 4; ++r) {
            int n = (r0 + r) & 4095;
            int qt = n >> 5, q31 = n & 31;
            q_ws[(size_t)(bh * 128 + qt) * 2048 + (dt * 64 + q31 + 32 * hd) * 8 + j] =
                f2bf(acc[mi][ni][r] * QSCALE);
          }
        }
      } else {
#pragma unroll
        for (int r = 0; r < 4; ++r)
          outf[(size_t)(r0 + r) * 512 + col] = acc[mi][ni][r] + bias[col];
      }
    }
  }
}

// Flash attention, causal. 1280 x 256-thread (4-wave) blocks, 32x32x16 MFMA.
// Block = (bh, q-group G, part s): stages kt in [s*T/S, (s+1)*T/S-1], T=2G+2,
// S=ceil((G+1)/8) <= 4. Wave wv computes qt=4G+wv restricted to kt <= qt/2.
// 5 blocks/CU resident. Partials (128 rows/part-block) -> merge (<=4 parts).
__global__ __launch_bounds__(256, 5) void attn_kernel(const ushort* __restrict__ Q,
                                                      const ushort* __restrict__ Kk,
                                                      const ushort* __restrict__ Vt,
                                                      ushort* __restrict__ po,
                                                      float* __restrict__ ml) {
  __shared__ ushort Ks[2][4096];
  __shared__ ushort Vs[2][4096];
  const int tid = threadIdx.x;
  const int lane = tid & 63, wv = tid >> 6;
  const int l31 = lane & 31, hf = lane >> 5;
  const int L = blockIdx.x;            // 0..1279
  const int p = L & 7;                 // XCD
  const int j2 = L >> 3;               // 0..159
  const int bh = p * 2 + (j2 & 1);     // each XCD: 2 bh only
  const int idx = 79 - (j2 >> 1);      // 0..79, heavy parts first
  int G = 31, s = idx;
  for (int g = 0; g < 32; ++g) {       // idx = prefix(G) + s, S(g) = (g>>3)+1
    int Sg = (g >> 3) + 1;
    if (s < Sg) { G = g; break; }
    s -= Sg;
  }
  const int S = (G >> 3) + 1;
  const int T = 2 * G + 2;             // staged range [0, 2G+1]
  const int klo = s * T / S;
  const int khi = (s + 1) * T / S - 1;
  const int qt = 4 * G + wv;           // this wave's q-tile (32 rows)
  const int ktmax = qt >> 1;           // diagonal tile index
  const int khi_w = (khi < ktmax) ? khi : ktmax;  // wave compute bound
  const int slot = bh * 80 + idx;
  const int qw = qt * 32;

  // Q B-frags (32x32x16): col = lane&31 = query, k = (lane>>5)*8+j = d - dt*16
  s16x8 aq[4];
  {
    const ushort* qp = Q + ((size_t)bh * 128 + qt) * 2048 + lane * 8;
#pragma unroll
    for (int dt = 0; dt < 4; ++dt) aq[dt] = *reinterpret_cast<const s16x8*>(qp + dt * 512);
  }

  f32x16 o[2] = {};  // O^T acc: db in {0,1}; col=lane&31=query, row=d
  float m = -1e30f;
  float l = 0.f;  // per-lane partial over this lane's 32 keys/tile

#define KVSTAGE(BUF, KT)                                                                  \
  do {                                                                                    \
    const ushort* kSrc = Kk + ((size_t)bh * 64 + (KT)) * 4096;                            \
    const ushort* vSrc = Vt + ((size_t)bh * 64 + (KT)) * 4096;                            \
    _Pragma("unroll") for (int c = 0; c < 2; ++c) {                                       \
      const int sb = (c * 256 + wv * 64) * 8;                                             \
      __builtin_amdgcn_global_load_lds(                                                   \
          (const __attribute__((address_space(1))) void*)(kSrc + sb + lane * 8),          \
          (__attribute__((address_space(3))) void*)(&Ks[BUF][0] + sb), 16, 0, 0);         \
      __builtin_amdgcn_global_load_lds(                                                   \
          (const __attribute__((address_space(1))) void*)(vSrc + sb + lane * 8),          \
          (__attribute__((address_space(3))) void*)(&Vs[BUF][0] + sb), 16, 0, 0);         \
    }                                                                                     \
  } while (0)

  KVSTAGE(0, klo);
  __syncthreads();
  int cur = 0;
  for (int kt = klo; kt <= khi; ++kt) {
    if (kt < khi) KVSTAGE(cur ^ 1, kt + 1);
    if (kt <= khi_w) {
      // K A-frags: row = lane&31 = key(+32*kb), k = (lane>>5)*8+j = d - dt*16
      const ushort* kl = &Ks[cur][lane * 8];
      s16x8 kf[8];
#pragma unroll
      for (int t = 0; t < 8; ++t) kf[t] = *reinterpret_cast<const s16x8*>(kl + t * 512);
      f32x16 st[2] = {};
      __builtin_amdgcn_s_setprio(1);
#pragma unroll
      for (int kb = 0; kb < 2; ++kb)
#pragma unroll
        for (int dt = 0; dt < 4; ++dt)
          st[kb] = __builtin_amdgcn_mfma_f32_32x32x16_bf16(kf[kb * 4 + dt], aq[dt],
                                                           st[kb], 0, 0, 0);
      __builtin_amdgcn_s_setprio(0);
      // C/D 32x32: col = lane&31 = query, row = (r&3)+8*(r>>2)+4*(lane>>5) = key(+32kb)
      if (kt == ktmax) {  // diagonal: mask key > query
        const int qg = qw + l31;
#pragma unroll
        for (int kb = 0; kb < 2; ++kb)
#pragma unroll
          for (int r = 0; r < 16; ++r)
            if (kt * 64 + kb * 32 + (r & 3) + 8 * (r >> 2) + 4 * hf > qg)
              st[kb][r] = -1e30f;
      }
      // lane-local max over this lane's 32 keys
      float mx[2];
#pragma unroll
      for (int kb = 0; kb < 2; ++kb) {
        float t0 = fmaxf(fmaxf(st[kb][0], st[kb][1]), fmaxf(st[kb][2], st[kb][3]));
        float t1 = fmaxf(fmaxf(st[kb][4], st[kb][5]), fmaxf(st[kb][6], st[kb][7]));
        float t2 = fmaxf(fmaxf(st[kb][8], st[kb][9]), fmaxf(st[kb][10], st[kb][11]));
        float t3 = fmaxf(fmaxf(st[kb][12], st[kb][13]), fmaxf(st[kb][14], st[kb][15]));
        mx[kb] = fmaxf(fmaxf(t0, t1), fmaxf(t2, t3));
      }
      float pm = fmaxf(mx[0], mx[1]);
      if (!__all(pm - m <= 8.0f)) {  // rare: joint (pair) max + rescale
        float pmf = fmaxf(pm, __shfl_xor(pm, 32));
        const float mn = fmaxf(m, pmf);
        const float al = __builtin_amdgcn_exp2f(m - mn);
        l *= al;
        m = mn;
#pragma unroll
        for (int db = 0; db < 2; ++db)
#pragma unroll
          for (int r = 0; r < 16; ++r) o[db][r] *= al;
      }
      // exp + pack into PV B-frags: pb[kc] k-elems = kc*16 + (lane>>5)*8 + j
      s16x8 pb[4];
      float rs = 0.f;
#pragma unroll
      for (int kb = 0; kb < 2; ++kb) {
        float e[16];
#pragma unroll
        for (int r = 0; r < 16; ++r) {
          e[r] = __builtin_amdgcn_exp2f(st[kb][r] - m);
          rs += e[r];
        }
        unsigned a0 = cvt_pk_bf16(e[0], e[1]), a1 = cvt_pk_bf16(e[2], e[3]);
        unsigned b0 = cvt_pk_bf16(e[4], e[5]), b1 = cvt_pk_bf16(e[6], e[7]);
        asm volatile("v_permlane32_swap_b32 %0, %1" : "+v"(a0), "+v"(b0));
        asm volatile("v_permlane32_swap_b32 %0, %1" : "+v"(a1), "+v"(b1));
        u32x4 w0;
        w0[0] = a0; w0[1] = a1; w0[2] = b0; w0[3] = b1;
        pb[kb * 2] = __builtin_bit_cast(s16x8, w0);
        unsigned c0 = cvt_pk_bf16(e[8], e[9]), c1 = cvt_pk_bf16(e[10], e[11]);
        unsigned d0 = cvt_pk_bf16(e[12], e[13]), d1 = cvt_pk_bf16(e[14], e[15]);
        asm volatile("v_permlane32_swap_b32 %0, %1" : "+v"(c0), "+v"(d0));
        asm volatile("v_permlane32_swap_b32 %0, %1" : "+v"(c1), "+v"(d1));
        u32x4 w1;
        w1[0] = c0; w1[1] = c1; w1[2] = d0; w1[3] = d1;
        pb[kb * 2 + 1] = __builtin_bit_cast(s16x8, w1);
      }
      l += rs;
      // V A-frags: row = lane&31 = d(+32*db), k = (lane>>5)*8+j = key - kc*16
      const ushort* vl = &Vs[cur][lane * 8];
      s16x8 vf[8];
#pragma unroll
      for (int t = 0; t < 8; ++t) vf[t] = *reinterpret_cast<const s16x8*>(vl + t * 512);
      __builtin_amdgcn_s_setprio(1);
#pragma unroll
      for (int db = 0; db < 2; ++db)
#pragma unroll
        for (int kc = 0; kc < 4; ++kc)
          o[db] = __builtin_amdgcn_mfma_f32_32x32x16_bf16(vf[db * 4 + kc], pb[kc],
                                                          o[db], 0, 0, 0);
      __builtin_amdgcn_s_setprio(0);
    }
    __syncthreads();  // drains staged loads + LDS reads; buffers safe to swap
    cur ^= 1;
  }
#undef KVSTAGE

  // l: pair-reduce (lane, lane+32) covers the full 64-key rows
  float lr = l + __shfl_xor(l, 32);
  const float linv = (lr > 0.f) ? (1.0f / lr) : 0.f;

  // Partial O: part-block row = wv*32 + (lane&31); d = db*32 + 8*(r>>2) + 4*hf + (r&3)
  const size_t pbase = ((size_t)slot * 128 + wv * 32 + l31) * 64;
#pragma unroll
  for (int db = 0; db < 2; ++db)
#pragma unroll
    for (int rg = 0; rg < 4; ++rg) {
      const int d0 = db * 32 + 8 * rg + 4 * hf;
      uint2 pk;
      pk.x = cvt_pk_bf16(o[db][rg * 4 + 0] * linv, o[db][rg * 4 + 1] * linv);
      pk.y = cvt_pk_bf16(o[db][rg * 4 + 2] * linv, o[db][rg * 4 + 3] * linv);
      *reinterpret_cast<uint2*>(po + pbase + d0) = pk;
    }
  if (hf == 0) {
    float2 v;
    v.x = m;
    v.y = lr;
    *reinterpret_cast<float2*>(ml + ((size_t)slot * 128 + wv * 32 + l31) * 2) = v;
  }
}

// Merge up to 4 parts per q-tile. 2048 blocks x 64 threads.
// prefix(G) = G + 4a(a-1) + a*b with a=G>>3, b=G&7; S = a+1.
__global__ __launch_bounds__(64) void attn_merge(const ushort* __restrict__ po,
                                                 const float* __restrict__ ml,
                                                 ushort* __restrict__ O) {
  const int M = blockIdx.x, tid = threadIdx.x;
  const int p = M & 7, q2 = M >> 3;   // q2 0..255
  const int bh = p * 2 + (q2 & 1);
  const int qt = q2 >> 1;             // 0..127
  const int G = qt >> 2;
  const int a = G >> 3, bq = G & 7;
  const int S = a + 1;
  const int slotBase = bh * 80 + (G + 4 * a * (a - 1) + a * bq);
  const int rowOff = (qt & 3) * 32 + (tid >> 1);
  const int dh = (tid & 1) * 32;
  float2 v0 = *reinterpret_cast<const float2*>(ml + ((size_t)(slotBase + 0) * 128 + rowOff) * 2);
  float2 v1 = {-1e30f, 0.f}, v2 = {-1e30f, 0.f}, v3 = {-1e30f, 0.f};
  if (S > 1) v1 = *reinterpret_cast<const float2*>(ml + ((size_t)(slotBase + 1) * 128 + rowOff) * 2);
  if (S > 2) v2 = *reinterpret_cast<const float2*>(ml + ((size_t)(slotBase + 2) * 128 + rowOff) * 2);
  if (S > 3) v3 = *reinterpret_cast<const float2*>(ml + ((size_t)(slotBase + 3) * 128 + rowOff) * 2);
  const float ms = fmaxf(fmaxf(v0.x, v1.x), fmaxf(v2.x, v3.x));
  float c0 = __builtin_amdgcn_exp2f(v0.x - ms) * v0.y;
  float c1 = __builtin_amdgcn_exp2f(v1.x - ms) * v1.y;
  float c2 = __builtin_amdgcn_exp2f(v2.x - ms) * v2.y;
  float c3 = __builtin_amdgcn_exp2f(v3.x - ms) * v3.y;
  const float inv = 1.0f / ((c0 + c1) + (c2 + c3));
  c0 *= inv; c1 *= inv; c2 *= inv; c3 *= inv;
  const int b = bh >> 3, h = bh & 7;
  const size_t rowo = (size_t)(b * 4096 + qt * 32 + (tid >> 1)) * 512 + h * 64 + dh;
  const ushort* p0 = po + ((size_t)(slotBase + 0) * 128 + rowOff) * 64 + dh;
  const ushort* p1 = po + ((size_t)(slotBase + 1) * 128 + rowOff) * 64 + dh;
  const ushort* p2 = po + ((size_t)(slotBase + 2) * 128 + rowOff) * 64 + dh;
  const ushort* p3 = po + ((size_t)(slotBase + 3) * 128 + rowOff) * 64 + dh;
#pragma unroll
  for (int j = 0; j < 4; ++j) {  // 4 x uint4 = full 32 bf16 of this d-half
    float acc0 = 0.f, acc1 = 0.f, acc2 = 0.f, acc3 = 0.f;
    float acc4 = 0.f, acc5 = 0.f, acc6 = 0.f, acc7 = 0.f;
    {
      uint4 aa = reinterpret_cast<const uint4*>(p0)[j];
      acc0 += c0 * bflo(aa.x); acc1 += c0 * bfhi(aa.x);
      acc2 += c0 * bflo(aa.y); acc3 += c0 * bfhi(aa.y);
      acc4 += c0 * bflo(aa.z); acc5 += c0 * bfhi(aa.z);
      acc6 += c0 * bflo(aa.w); acc7 += c0 * bfhi(aa.w);
    }
    if (S > 1) {
      uint4 aa = reinterpret_cast<const uint4*>(p1)[j];
      acc0 += c1 * bflo(aa.x); acc1 += c1 * bfhi(aa.x);
      acc2 += c1 * bflo(aa.y); acc3 += c1 * bfhi(aa.y);
      acc4 += c1 * bflo(aa.z); acc5 += c1 * bfhi(aa.z);
      acc6 += c1 * bflo(aa.w); acc7 += c1 * bfhi(aa.w);
    }
    if (S > 2) {
      uint4 aa = reinterpret_cast<const uint4*>(p2)[j];
      acc0 += c2 * bflo(aa.x); acc1 += c2 * bfhi(aa.x);
      acc2 += c2 * bflo(aa.y); acc3 += c2 * bfhi(aa.y);
      acc4 += c2 * bflo(aa.z); acc5 += c2 * bfhi(aa.z);
      acc6 += c2 * bflo(aa.w); acc7 += c2 * bfhi(aa.w);
    }
    if (S > 3) {
      uint4 aa = reinterpret_cast<const uint4*>(p3)[j];
      acc0 += c3 * bflo(aa.x); acc1 += c3 * bfhi(aa.x);
      acc2 += c3 * bflo(aa.y); acc3 += c3 * bfhi(aa.y);
      acc4 += c3 * bflo(aa.z); acc5 += c3 * bfhi(aa.z);
      acc6 += c3 * bflo(aa.w); acc7 += c3 * bfhi(aa.w);
    }
    uint4 out;
    out.x = cvt_pk_bf16(acc0, acc1);
    out.y = cvt_pk_bf16(acc2, acc3);
    out.z = cvt_pk_bf16(acc4, acc5);
    out.w = cvt_pk_bf16(acc6, acc7);
    reinterpret_cast<uint4*>(&O[rowo])[j] = out;
  }
}

extern "C" void kernel_launch(void* const* d_in, const int* in_sizes, int n_in,
                              void* d_out, int out_size, void* d_ws, size_t ws_size,
                              hipStream_t stream) {
  const float* x = (const float*)d_in[0];       // [2,4096,512]
  const float* w_qkv = (const float*)d_in[1];   // [1536,512]
  const float* w_proj = (const float*)d_in[2];  // [512,512]
  const float* b_proj = (const float*)d_in[3];  // [512]
  float* out = (float*)d_out;                   // [2,4096,512]

  ushort* xb = (ushort*)d_ws;                       // 8192*512
  ushort* wqkvb = xb + (size_t)8192 * 512;          // 1536*512
  ushort* wprojb = wqkvb + (size_t)1536 * 512;      // 512*512
  ushort* qws = wprojb + (size_t)512 * 512;         // 16*128*2048
  ushort* kws = qws + (size_t)16 * 4096 * 64;       // 16*64*4096
  ushort* vtws = kws + (size_t)16 * 4096 * 64;
  ushort* ows = vtws + (size_t)16 * 4096 * 64;      // 8192*512

  cvt_all<<<5120, 256, 0, stream>>>(x, w_qkv, w_proj, xb, wqkvb, wprojb);

  gemm_bt<0><<<dim3(12, 64), 256, 0, stream>>>(xb, wqkvb, qws, kws, vtws, nullptr, nullptr);

  // Partials at ws tail: po = 1280 part-blocks x 128 rows x 64 d bf16 = 21.0MB,
  // ml = 1.31MB; total through tail = 66.4MB <= 70.8MB (proven ws size).
  ushort* po = ows + (size_t)8192 * 512;
  float* ml = (float*)(po + (size_t)1280 * 128 * 64);

  attn_kernel<<<1280, 256, 0, stream>>>(qws, kws, vtws, po, ml);
  attn_merge<<<2048, 64, 0, stream>>>(po, ml, ows);

  gemm_bt<1><<<dim3(4, 64), 256, 0, stream>>>(ows, wprojb, nullptr, nullptr, nullptr, out,
                                              b_proj);
}

// Round 21
// 111.350 us; speedup vs baseline: 3.2911x; 3.2911x over previous
//
#include <hip/hip_runtime.h>
#include <hip/hip_bf16.h>

// MultiHeadCausalSelfAttention: B=2, N=4096, C=512, H=8, D=64, causal, fp32 in/out.
// Pipeline: cvt(fused) -> QKV GEMM (scatter Q,K,V frag layouts) -> attn(+merge) -> proj.
// R21: R20 with launch_bounds(256,5) -> (256,4). R20's 5/CU bound capped VGPR at ~96
// and spilled (VGPR=48, 667MB scratch writes). (256,4) is the R18-proven no-spill cap;
// 1280 equal-length (<=16 iter) blocks now run 4/CU resident + 256 backfill.

typedef __attribute__((ext_vector_type(8))) short s16x8;    // 8 bf16 = MFMA A/B frag
typedef __attribute__((ext_vector_type(4))) float f32x4;    // 16x16 C/D frag
typedef __attribute__((ext_vector_type(16))) float f32x16;  // 32x32 C/D frag
typedef __attribute__((ext_vector_type(4))) unsigned u32x4;

#define QSCALE 0.18033688011112042f  // D^-0.5 * log2(e), folded into Q

__device__ __forceinline__ ushort f2bf(float f) {
  unsigned u = __float_as_uint(f);
  u = (u + 0x7FFFu + ((u >> 16) & 1u)) >> 16;  // RNE
  return (ushort)u;
}

__device__ __forceinline__ unsigned cvt_pk_bf16(float a, float b) {
  unsigned r;
  asm("v_cvt_pk_bf16_f32 %0, %1, %2" : "=v"(r) : "v"(a), "v"(b));
  return r;  // low16 = bf16(a), high16 = bf16(b)
}

__device__ __forceinline__ float bflo(unsigned u) { return __uint_as_float(u << 16); }
__device__ __forceinline__ float bfhi(unsigned u) { return __uint_as_float(u & 0xffff0000u); }

// One fused cvt for x (1048576 float4), w_qkv (196608), w_proj (65536).
__global__ __launch_bounds__(256) void cvt_all(const float* __restrict__ x,
                                               const float* __restrict__ wq,
                                               const float* __restrict__ wp,
                                               ushort* __restrict__ xb,
                                               ushort* __restrict__ wqb,
                                               ushort* __restrict__ wpb) {
  int i = blockIdx.x * 256 + threadIdx.x;
  const float* src;
  ushort* dst;
  int off;
  if (i < 1048576) {
    src = x; dst = xb; off = i;
  } else if (i < 1245184) {
    src = wq; dst = wqb; off = i - 1048576;
  } else {
    src = wp; dst = wpb; off = i - 1245184;
  }
  float4 v = reinterpret_cast<const float4*>(src)[off];
  ushort4 o;
  o.x = f2bf(v.x); o.y = f2bf(v.y); o.z = f2bf(v.z); o.w = f2bf(v.w);
  reinterpret_cast<ushort4*>(dst)[off] = o;
}

// C = A[M,512] @ W[Nout,512]^T, bf16 MFMA 16x16, 128x128 tile, 4 waves, BK=32, dbuf.
// EPI 0 scatter layouts (for 32x32 attn frags); EPI 1: fp32 out + bias.
template <int EPI>
__global__ __launch_bounds__(256) void gemm_bt(const ushort* __restrict__ A,
                                               const ushort* __restrict__ W,
                                               ushort* __restrict__ q_ws,
                                               ushort* __restrict__ k_ws,
                                               ushort* __restrict__ vt_ws,
                                               float* __restrict__ outf,
                                               const float* __restrict__ bias) {
  __shared__ ushort As[2][128 * 32];
  __shared__ ushort Bs[2][128 * 32];
  const int tid = threadIdx.x;
  const int lane = tid & 63, wv = tid >> 6;
  const int wm = wv >> 1, wn = wv & 1;
  const int l15 = lane & 15, g = lane >> 4;
  const int tm = blockIdx.y * 128, tn = blockIdx.x * 128;

  f32x4 acc[4][4] = {};

#define GSTAGE(BUF, K0)                                                                    \
  do {                                                                                     \
    _Pragma("unroll") for (int it = 0; it < 2; ++it) {                                     \
      int slot = it * 256 + tid;                                                           \
      int row = slot >> 2;                                                                 \
      int ch = (slot & 3) ^ ((row >> 1) & 3);                                              \
      const int sb = (it * 256 + wv * 64) * 8; /* wave-uniform LDS base (ushorts) */       \
      __builtin_amdgcn_global_load_lds(                                                    \
          (const __attribute__((address_space(1))) void*)(A + (size_t)(tm + row) * 512 +   \
                                                          (K0) + ch * 8),                  \
          (__attribute__((address_space(3))) void*)(&As[BUF][0] + sb), 16, 0, 0);          \
      __builtin_amdgcn_global_load_lds(                                                    \
          (const __attribute__((address_space(1))) void*)(W + (size_t)(tn + row) * 512 +   \
                                                          (K0) + ch * 8),                  \
          (__attribute__((address_space(3))) void*)(&Bs[BUF][0] + sb), 16, 0, 0);          \
    }                                                                                      \
  } while (0)

  GSTAGE(0, 0);
  __syncthreads();
  int cur = 0;
  for (int t = 0; t < 16; ++t) {
    if (t < 15) GSTAGE(cur ^ 1, (t + 1) * 32);
    s16x8 af[4], bfr[4];
#pragma unroll
    for (int i = 0; i < 4; ++i) {
      int Ra = wm * 64 + i * 16 + l15;
      af[i] = reinterpret_cast<const s16x8*>(&As[cur][0])[Ra * 4 + (g ^ ((Ra >> 1) & 3))];
      int Rb = wn * 64 + i * 16 + l15;
      bfr[i] = reinterpret_cast<const s16x8*>(&Bs[cur][0])[Rb * 4 + (g ^ ((Rb >> 1) & 3))];
    }
#pragma unroll
    for (int mi = 0; mi < 4; ++mi)
#pragma unroll
      for (int ni = 0; ni < 4; ++ni)
        acc[mi][ni] =
            __builtin_amdgcn_mfma_f32_16x16x32_bf16(af[mi], bfr[ni], acc[mi][ni], 0, 0, 0);
    __syncthreads();
    cur ^= 1;
  }
#undef GSTAGE

  // C/D (16x16): col = lane&15, row = (lane>>4)*4 + reg
  const int rowb = tm + wm * 64 + g * 4;
  const int colb = tn + wn * 64 + l15;
#pragma unroll
  for (int mi = 0; mi < 4; ++mi) {
#pragma unroll
    for (int ni = 0; ni < 4; ++ni) {
      int r0 = rowb + mi * 16;
      int col = colb + ni * 16;
      if (EPI == 0) {
        int i3 = col >> 9, h = (col >> 6) & 7, d = col & 63;
        int b = r0 >> 12;
        int bh = b * 8 + h;
        if (i3 == 2) {  // V: 4 consecutive keys -> ushort4
          int n0 = r0 & 4095;
          int kt64 = n0 >> 6, key64 = n0 & 63;
          int kc = key64 >> 4, hk = (key64 >> 3) & 1, j0 = key64 & 7;
          int db = d >> 5, d31 = d & 31;
          ushort4 pk;
          pk.x = f2bf(acc[mi][ni][0]);
          pk.y = f2bf(acc[mi][ni][1]);
          pk.z = f2bf(acc[mi][ni][2]);
          pk.w = f2bf(acc[mi][ni][3]);
          *reinterpret_cast<ushort4*>(vt_ws + (size_t)(bh * 64 + kt64) * 4096 +
                                      ((db * 4 + kc) * 64 + d31 + 32 * hk) * 8 + j0) = pk;
        } else if (i3 == 1) {  // K: scalar x4
          int dt = d >> 4, hd = (d >> 3) & 1, j = d & 7;
#pragma unroll
          for (int r = 0; r < 4; ++r) {
            int n = (r0 + r) & 4095;
            int kt64 = n >> 6, key64 = n & 63;
            int kb = key64 >> 5, key31 = key64 & 31;
            k_ws[(size_t)(bh * 64 + kt64) * 4096 +
                 ((kb * 4 + dt) * 64 + key31 + 32 * hd) * 8 + j] = f2bf(acc[mi][ni][r]);
          }
        } else {  // Q: scalar x4, scaled
          int dt = d >> 4, hd = (d >> 3) & 1, j = d & 7;
#pragma unroll
          for (int r = 0; r < 4; ++r) {
            int n = (r0 + r) & 4095;
            int qt = n >> 5, q31 = n & 31;
            q_ws[(size_t)(bh * 128 + qt) * 2048 + (dt * 64 + q31 + 32 * hd) * 8 + j] =
                f2bf(acc[mi][ni][r] * QSCALE);
          }
        }
      } else {
#pragma unroll
        for (int r = 0; r < 4; ++r)
          outf[(size_t)(r0 + r) * 512 + col] = acc[mi][ni][r] + bias[col];
      }
    }
  }
}

// Flash attention, causal. 1280 x 256-thread (4-wave) blocks, 32x32x16 MFMA.
// Block = (bh, q-group G, part s): stages kt in [s*T/S, (s+1)*T/S-1], T=2G+2,
// S=ceil((G+1)/8) <= 4. Wave wv computes qt=4G+wv restricted to kt <= qt/2.
// 4 blocks/CU resident + backfill. Partials (128 rows/part-block) -> merge.
__global__ __launch_bounds__(256, 4) void attn_kernel(const ushort* __restrict__ Q,
                                                      const ushort* __restrict__ Kk,
                                                      const ushort* __restrict__ Vt,
                                                      ushort* __restrict__ po,
                                                      float* __restrict__ ml) {
  __shared__ ushort Ks[2][4096];
  __shared__ ushort Vs[2][4096];
  const int tid = threadIdx.x;
  const int lane = tid & 63, wv = tid >> 6;
  const int l31 = lane & 31, hf = lane >> 5;
  const int L = blockIdx.x;            // 0..1279
  const int p = L & 7;                 // XCD
  const int j2 = L >> 3;               // 0..159
  const int bh = p * 2 + (j2 & 1);     // each XCD: 2 bh only
  const int idx = 79 - (j2 >> 1);      // 0..79, heavy parts first
  int G = 31, s = idx;
  for (int g = 0; g < 32; ++g) {       // idx = prefix(G) + s, S(g) = (g>>3)+1
    int Sg = (g >> 3) + 1;
    if (s < Sg) { G = g; break; }
    s -= Sg;
  }
  const int S = (G >> 3) + 1;
  const int T = 2 * G + 2;             // staged range [0, 2G+1]
  const int klo = s * T / S;
  const int khi = (s + 1) * T / S - 1;
  const int qt = 4 * G + wv;           // this wave's q-tile (32 rows)
  const int ktmax = qt >> 1;           // diagonal tile index
  const int khi_w = (khi < ktmax) ? khi : ktmax;  // wave compute bound
  const int slot = bh * 80 + idx;
  const int qw = qt * 32;

  // Q B-frags (32x32x16): col = lane&31 = query, k = (lane>>5)*8+j = d - dt*16
  s16x8 aq[4];
  {
    const ushort* qp = Q + ((size_t)bh * 128 + qt) * 2048 + lane * 8;
#pragma unroll
    for (int dt = 0; dt < 4; ++dt) aq[dt] = *reinterpret_cast<const s16x8*>(qp + dt * 512);
  }

  f32x16 o[2] = {};  // O^T acc: db in {0,1}; col=lane&31=query, row=d
  float m = -1e30f;
  float l = 0.f;  // per-lane partial over this lane's 32 keys/tile

#define KVSTAGE(BUF, KT)                                                                  \
  do {                                                                                    \
    const ushort* kSrc = Kk + ((size_t)bh * 64 + (KT)) * 4096;                            \
    const ushort* vSrc = Vt + ((size_t)bh * 64 + (KT)) * 4096;                            \
    _Pragma("unroll") for (int c = 0; c < 2; ++c) {                                       \
      const int sb = (c * 256 + wv * 64) * 8;                                             \
      __builtin_amdgcn_global_load_lds(                                                   \
          (const __attribute__((address_space(1))) void*)(kSrc + sb + lane * 8),          \
          (__attribute__((address_space(3))) void*)(&Ks[BUF][0] + sb), 16, 0, 0);         \
      __builtin_amdgcn_global_load_lds(                                                   \
          (const __attribute__((address_space(1))) void*)(vSrc + sb + lane * 8),          \
          (__attribute__((address_space(3))) void*)(&Vs[BUF][0] + sb), 16, 0, 0);         \
    }                                                                                     \
  } while (0)

  KVSTAGE(0, klo);
  __syncthreads();
  int cur = 0;
  for (int kt = klo; kt <= khi; ++kt) {
    if (kt < khi) KVSTAGE(cur ^ 1, kt + 1);
    if (kt <= khi_w) {
      // K A-frags: row = lane&31 = key(+32*kb), k = (lane>>5)*8+j = d - dt*16
      const ushort* kl = &Ks[cur][lane * 8];
      s16x8 kf[8];
#pragma unroll
      for (int t = 0; t < 8; ++t) kf[t] = *reinterpret_cast<const s16x8*>(kl + t * 512);
      f32x16 st[2] = {};
      __builtin_amdgcn_s_setprio(1);
#pragma unroll
      for (int kb = 0; kb < 2; ++kb)
#pragma unroll
        for (int dt = 0; dt < 4; ++dt)
          st[kb] = __builtin_amdgcn_mfma_f32_32x32x16_bf16(kf[kb * 4 + dt], aq[dt],
                                                           st[kb], 0, 0, 0);
      __builtin_amdgcn_s_setprio(0);
      // C/D 32x32: col = lane&31 = query, row = (r&3)+8*(r>>2)+4*(lane>>5) = key(+32kb)
      if (kt == ktmax) {  // diagonal: mask key > query
        const int qg = qw + l31;
#pragma unroll
        for (int kb = 0; kb < 2; ++kb)
#pragma unroll
          for (int r = 0; r < 16; ++r)
            if (kt * 64 + kb * 32 + (r & 3) + 8 * (r >> 2) + 4 * hf > qg)
              st[kb][r] = -1e30f;
      }
      // lane-local max over this lane's 32 keys
      float mx[2];
#pragma unroll
      for (int kb = 0; kb < 2; ++kb) {
        float t0 = fmaxf(fmaxf(st[kb][0], st[kb][1]), fmaxf(st[kb][2], st[kb][3]));
        float t1 = fmaxf(fmaxf(st[kb][4], st[kb][5]), fmaxf(st[kb][6], st[kb][7]));
        float t2 = fmaxf(fmaxf(st[kb][8], st[kb][9]), fmaxf(st[kb][10], st[kb][11]));
        float t3 = fmaxf(fmaxf(st[kb][12], st[kb][13]), fmaxf(st[kb][14], st[kb][15]));
        mx[kb] = fmaxf(fmaxf(t0, t1), fmaxf(t2, t3));
      }
      float pm = fmaxf(mx[0], mx[1]);
      if (!__all(pm - m <= 8.0f)) {  // rare: joint (pair) max + rescale
        float pmf = fmaxf(pm, __shfl_xor(pm, 32));
        const float mn = fmaxf(m, pmf);
        const float al = __builtin_amdgcn_exp2f(m - mn);
        l *= al;
        m = mn;
#pragma unroll
        for (int db = 0; db < 2; ++db)
#pragma unroll
          for (int r = 0; r < 16; ++r) o[db][r] *= al;
      }
      // exp + pack into PV B-frags: pb[kc] k-elems = kc*16 + (lane>>5)*8 + j
      s16x8 pb[4];
      float rs = 0.f;
#pragma unroll
      for (int kb = 0; kb < 2; ++kb) {
        float e[16];
#pragma unroll
        for (int r = 0; r < 16; ++r) {
          e[r] = __builtin_amdgcn_exp2f(st[kb][r] - m);
          rs += e[r];
        }
        unsigned a0 = cvt_pk_bf16(e[0], e[1]), a1 = cvt_pk_bf16(e[2], e[3]);
        unsigned b0 = cvt_pk_bf16(e[4], e[5]), b1 = cvt_pk_bf16(e[6], e[7]);
        asm volatile("v_permlane32_swap_b32 %0, %1" : "+v"(a0), "+v"(b0));
        asm volatile("v_permlane32_swap_b32 %0, %1" : "+v"(a1), "+v"(b1));
        u32x4 w0;
        w0[0] = a0; w0[1] = a1; w0[2] = b0; w0[3] = b1;
        pb[kb * 2] = __builtin_bit_cast(s16x8, w0);
        unsigned c0 = cvt_pk_bf16(e[8], e[9]), c1 = cvt_pk_bf16(e[10], e[11]);
        unsigned d0 = cvt_pk_bf16(e[12], e[13]), d1 = cvt_pk_bf16(e[14], e[15]);
        asm volatile("v_permlane32_swap_b32 %0, %1" : "+v"(c0), "+v"(d0));
        asm volatile("v_permlane32_swap_b32 %0, %1" : "+v"(c1), "+v"(d1));
        u32x4 w1;
        w1[0] = c0; w1[1] = c1; w1[2] = d0; w1[3] = d1;
        pb[kb * 2 + 1] = __builtin_bit_cast(s16x8, w1);
      }
      l += rs;
      // V A-frags: row = lane&31 = d(+32*db), k = (lane>>5)*8+j = key - kc*16
      const ushort* vl = &Vs[cur][lane * 8];
      s16x8 vf[8];
#pragma unroll
      for (int t = 0; t < 8; ++t) vf[t] = *reinterpret_cast<const s16x8*>(vl + t * 512);
      __builtin_amdgcn_s_setprio(1);
#pragma unroll
      for (int db = 0; db < 2; ++db)
#pragma unroll
        for (int kc = 0; kc < 4; ++kc)
          o[db] = __builtin_amdgcn_mfma_f32_32x32x16_bf16(vf[db * 4 + kc], pb[kc],
                                                          o[db], 0, 0, 0);
      __builtin_amdgcn_s_setprio(0);
    }
    __syncthreads();  // drains staged loads + LDS reads; buffers safe to swap
    cur ^= 1;
  }
#undef KVSTAGE

  // l: pair-reduce (lane, lane+32) covers the full 64-key rows
  float lr = l + __shfl_xor(l, 32);
  const float linv = (lr > 0.f) ? (1.0f / lr) : 0.f;

  // Partial O: part-block row = wv*32 + (lane&31); d = db*32 + 8*(r>>2) + 4*hf + (r&3)
  const size_t pbase = ((size_t)slot * 128 + wv * 32 + l31) * 64;
#pragma unroll
  for (int db = 0; db < 2; ++db)
#pragma unroll
    for (int rg = 0; rg < 4; ++rg) {
      const int d0 = db * 32 + 8 * rg + 4 * hf;
      uint2 pk;
      pk.x = cvt_pk_bf16(o[db][rg * 4 + 0] * linv, o[db][rg * 4 + 1] * linv);
      pk.y = cvt_pk_bf16(o[db][rg * 4 + 2] * linv, o[db][rg * 4 + 3] * linv);
      *reinterpret_cast<uint2*>(po + pbase + d0) = pk;
    }
  if (hf == 0) {
    float2 v;
    v.x = m;
    v.y = lr;
    *reinterpret_cast<float2*>(ml + ((size_t)slot * 128 + wv * 32 + l31) * 2) = v;
  }
}

// Merge up to 4 parts per q-tile. 2048 blocks x 64 threads.
// prefix(G) = G + 4a(a-1) + a*b with a=G>>3, b=G&7; S = a+1.
__global__ __launch_bounds__(64) void attn_merge(const ushort* __restrict__ po,
                                                 const float* __restrict__ ml,
                                                 ushort* __restrict__ O) {
  const int M = blockIdx.x, tid = threadIdx.x;
  const int p = M & 7, q2 = M >> 3;   // q2 0..255
  const int bh = p * 2 + (q2 & 1);
  const int qt = q2 >> 1;             // 0..127
  const int G = qt >> 2;
  const int a = G >> 3, bq = G & 7;
  const int S = a + 1;
  const int slotBase = bh * 80 + (G + 4 * a * (a - 1) + a * bq);
  const int rowOff = (qt & 3) * 32 + (tid >> 1);
  const int dh = (tid & 1) * 32;
  float2 v0 = *reinterpret_cast<const float2*>(ml + ((size_t)(slotBase + 0) * 128 + rowOff) * 2);
  float2 v1 = {-1e30f, 0.f}, v2 = {-1e30f, 0.f}, v3 = {-1e30f, 0.f};
  if (S > 1) v1 = *reinterpret_cast<const float2*>(ml + ((size_t)(slotBase + 1) * 128 + rowOff) * 2);
  if (S > 2) v2 = *reinterpret_cast<const float2*>(ml + ((size_t)(slotBase + 2) * 128 + rowOff) * 2);
  if (S > 3) v3 = *reinterpret_cast<const float2*>(ml + ((size_t)(slotBase + 3) * 128 + rowOff) * 2);
  const float ms = fmaxf(fmaxf(v0.x, v1.x), fmaxf(v2.x, v3.x));
  float c0 = __builtin_amdgcn_exp2f(v0.x - ms) * v0.y;
  float c1 = __builtin_amdgcn_exp2f(v1.x - ms) * v1.y;
  float c2 = __builtin_amdgcn_exp2f(v2.x - ms) * v2.y;
  float c3 = __builtin_amdgcn_exp2f(v3.x - ms) * v3.y;
  const float inv = 1.0f / ((c0 + c1) + (c2 + c3));
  c0 *= inv; c1 *= inv; c2 *= inv; c3 *= inv;
  const int b = bh >> 3, h = bh & 7;
  const size_t rowo = (size_t)(b * 4096 + qt * 32 + (tid >> 1)) * 512 + h * 64 + dh;
  const ushort* p0 = po + ((size_t)(slotBase + 0) * 128 + rowOff) * 64 + dh;
  const ushort* p1 = po + ((size_t)(slotBase + 1) * 128 + rowOff) * 64 + dh;
  const ushort* p2 = po + ((size_t)(slotBase + 2) * 128 + rowOff) * 64 + dh;
  const ushort* p3 = po + ((size_t)(slotBase + 3) * 128 + rowOff) * 64 + dh;
#pragma unroll
  for (int j = 0; j < 4; ++j) {  // 4 x uint4 = full 32 bf16 of this d-half
    float acc0 = 0.f, acc1 = 0.f, acc2 = 0.f, acc3 = 0.f;
    float acc4 = 0.f, acc5 = 0.f, acc6 = 0.f, acc7 = 0.f;
    {
      uint4 aa = reinterpret_cast<const uint4*>(p0)[j];
      acc0 += c0 * bflo(aa.x); acc1 += c0 * bfhi(aa.x);
      acc2 += c0 * bflo(aa.y); acc3 += c0 * bfhi(aa.y);
      acc4 += c0 * bflo(aa.z); acc5 += c0 * bfhi(aa.z);
      acc6 += c0 * bflo(aa.w); acc7 += c0 * bfhi(aa.w);
    }
    if (S > 1) {
      uint4 aa = reinterpret_cast<const uint4*>(p1)[j];
      acc0 += c1 * bflo(aa.x); acc1 += c1 * bfhi(aa.x);
      acc2 += c1 * bflo(aa.y); acc3 += c1 * bfhi(aa.y);
      acc4 += c1 * bflo(aa.z); acc5 += c1 * bfhi(aa.z);
      acc6 += c1 * bflo(aa.w); acc7 += c1 * bfhi(aa.w);
    }
    if (S > 2) {
      uint4 aa = reinterpret_cast<const uint4*>(p2)[j];
      acc0 += c2 * bflo(aa.x); acc1 += c2 * bfhi(aa.x);
      acc2 += c2 * bflo(aa.y); acc3 += c2 * bfhi(aa.y);
      acc4 += c2 * bflo(aa.z); acc5 += c2 * bfhi(aa.z);
      acc6 += c2 * bflo(aa.w); acc7 += c2 * bfhi(aa.w);
    }
    if (S > 3) {
      uint4 aa = reinterpret_cast<const uint4*>(p3)[j];
      acc0 += c3 * bflo(aa.x); acc1 += c3 * bfhi(aa.x);
      acc2 += c3 * bflo(aa.y); acc3 += c3 * bfhi(aa.y);
      acc4 += c3 * bflo(aa.z); acc5 += c3 * bfhi(aa.z);
      acc6 += c3 * bflo(aa.w); acc7 += c3 * bfhi(aa.w);
    }
    uint4 out;
    out.x = cvt_pk_bf16(acc0, acc1);
    out.y = cvt_pk_bf16(acc2, acc3);
    out.z = cvt_pk_bf16(acc4, acc5);
    out.w = cvt_pk_bf16(acc6, acc7);
    reinterpret_cast<uint4*>(&O[rowo])[j] = out;
  }
}

extern "C" void kernel_launch(void* const* d_in, const int* in_sizes, int n_in,
                              void* d_out, int out_size, void* d_ws, size_t ws_size,
                              hipStream_t stream) {
  const float* x = (const float*)d_in[0];       // [2,4096,512]
  const float* w_qkv = (const float*)d_in[1];   // [1536,512]
  const float* w_proj = (const float*)d_in[2];  // [512,512]
  const float* b_proj = (const float*)d_in[3];  // [512]
  float* out = (float*)d_out;                   // [2,4096,512]

  ushort* xb = (ushort*)d_ws;                       // 8192*512
  ushort* wqkvb = xb + (size_t)8192 * 512;          // 1536*512
  ushort* wprojb = wqkvb + (size_t)1536 * 512;      // 512*512
  ushort* qws = wprojb + (size_t)512 * 512;         // 16*128*2048
  ushort* kws = qws + (size_t)16 * 4096 * 64;       // 16*64*4096
  ushort* vtws = kws + (size_t)16 * 4096 * 64;
  ushort* ows = vtws + (size_t)16 * 4096 * 64;      // 8192*512

  cvt_all<<<5120, 256, 0, stream>>>(x, w_qkv, w_proj, xb, wqkvb, wprojb);

  gemm_bt<0><<<dim3(12, 64), 256, 0, stream>>>(xb, wqkvb, qws, kws, vtws, nullptr, nullptr);

  // Partials at ws tail: po = 1280 part-blocks x 128 rows x 64 d bf16 = 21.0MB,
  // ml = 1.31MB; total through tail = 66.4MB <= 70.8MB (proven ws size).
  ushort* po = ows + (size_t)8192 * 512;
  float* ml = (float*)(po + (size_t)1280 * 128 * 64);

  attn_kernel<<<1280, 256, 0, stream>>>(qws, kws, vtws, po, ml);
  attn_merge<<<2048, 64, 0, stream>>>(po, ml, ows);

  gemm_bt<1><<<dim3(4, 64), 256, 0, stream>>>(ows, wprojb, nullptr, nullptr, nullptr, out,
                                              b_proj);
}

// Round 22
// 102.406 us; speedup vs baseline: 3.5785x; 1.0873x over previous
//
#include <hip/hip_runtime.h>
#include <hip/hip_bf16.h>

// MultiHeadCausalSelfAttention: B=2, N=4096, C=512, H=8, D=64, causal, fp32 in/out.
// Pipeline: cvt(fused) -> QKV GEMM (scatter Q,K,V frag layouts) -> attn(+merge) -> proj.
// R22: attn reverted to R18 (proven 56.5us; R19-21 equal-length split NET-NEGATIVE).
//      GEMMs: 1-D grid + bijective XCD-chunk swizzle (each XCD owns contiguous
//      M-panels -> x panels fetched by exactly one L2; kills ~8x x over-fetch).

typedef __attribute__((ext_vector_type(8))) short s16x8;    // 8 bf16 = MFMA A/B frag
typedef __attribute__((ext_vector_type(4))) float f32x4;    // 16x16 C/D frag
typedef __attribute__((ext_vector_type(16))) float f32x16;  // 32x32 C/D frag
typedef __attribute__((ext_vector_type(4))) unsigned u32x4;

#define QSCALE 0.18033688011112042f  // D^-0.5 * log2(e), folded into Q

__device__ __forceinline__ ushort f2bf(float f) {
  unsigned u = __float_as_uint(f);
  u = (u + 0x7FFFu + ((u >> 16) & 1u)) >> 16;  // RNE
  return (ushort)u;
}

__device__ __forceinline__ unsigned cvt_pk_bf16(float a, float b) {
  unsigned r;
  asm("v_cvt_pk_bf16_f32 %0, %1, %2" : "=v"(r) : "v"(a), "v"(b));
  return r;  // low16 = bf16(a), high16 = bf16(b)
}

__device__ __forceinline__ float bflo(unsigned u) { return __uint_as_float(u << 16); }
__device__ __forceinline__ float bfhi(unsigned u) { return __uint_as_float(u & 0xffff0000u); }

// One fused cvt for x (1048576 float4), w_qkv (196608), w_proj (65536).
__global__ __launch_bounds__(256) void cvt_all(const float* __restrict__ x,
                                               const float* __restrict__ wq,
                                               const float* __restrict__ wp,
                                               ushort* __restrict__ xb,
                                               ushort* __restrict__ wqb,
                                               ushort* __restrict__ wpb) {
  int i = blockIdx.x * 256 + threadIdx.x;
  const float* src;
  ushort* dst;
  int off;
  if (i < 1048576) {
    src = x; dst = xb; off = i;
  } else if (i < 1245184) {
    src = wq; dst = wqb; off = i - 1048576;
  } else {
    src = wp; dst = wpb; off = i - 1245184;
  }
  float4 v = reinterpret_cast<const float4*>(src)[off];
  ushort4 o;
  o.x = f2bf(v.x); o.y = f2bf(v.y); o.z = f2bf(v.z); o.w = f2bf(v.w);
  reinterpret_cast<ushort4*>(dst)[off] = o;
}

// C = A[M,512] @ W[Nout,512]^T, bf16 MFMA 16x16, 128x128 tile, 4 waves, BK=32, dbuf.
// 1-D grid, bijective XCD-chunk swizzle: n = (orig&7)*(nwg/8) + (orig>>3);
// bx = n % NT (col tile), by = n / NT (row tile) -> each XCD owns contiguous rows.
// EPI 0 scatter layouts (for 32x32 attn frags); EPI 1: fp32 out + bias.
template <int EPI, int NT>
__global__ __launch_bounds__(256) void gemm_bt(const ushort* __restrict__ A,
                                               const ushort* __restrict__ W,
                                               ushort* __restrict__ q_ws,
                                               ushort* __restrict__ k_ws,
                                               ushort* __restrict__ vt_ws,
                                               float* __restrict__ outf,
                                               const float* __restrict__ bias) {
  __shared__ ushort As[2][128 * 32];
  __shared__ ushort Bs[2][128 * 32];
  const int tid = threadIdx.x;
  const int lane = tid & 63, wv = tid >> 6;
  const int wm = wv >> 1, wn = wv & 1;
  const int l15 = lane & 15, g = lane >> 4;
  const int nswz = ((int)blockIdx.x & 7) * ((int)gridDim.x >> 3) + ((int)blockIdx.x >> 3);
  const int tm = (nswz / NT) * 128, tn = (nswz % NT) * 128;

  f32x4 acc[4][4] = {};

#define GSTAGE(BUF, K0)                                                                    \
  do {                                                                                     \
    _Pragma("unroll") for (int it = 0; it < 2; ++it) {                                     \
      int slot = it * 256 + tid;                                                           \
      int row = slot >> 2;                                                                 \
      int ch = (slot & 3) ^ ((row >> 1) & 3);                                              \
      const int sb = (it * 256 + wv * 64) * 8; /* wave-uniform LDS base (ushorts) */       \
      __builtin_amdgcn_global_load_lds(                                                    \
          (const __attribute__((address_space(1))) void*)(A + (size_t)(tm + row) * 512 +   \
                                                          (K0) + ch * 8),                  \
          (__attribute__((address_space(3))) void*)(&As[BUF][0] + sb), 16, 0, 0);          \
      __builtin_amdgcn_global_load_lds(                                                    \
          (const __attribute__((address_space(1))) void*)(W + (size_t)(tn + row) * 512 +   \
                                                          (K0) + ch * 8),                  \
          (__attribute__((address_space(3))) void*)(&Bs[BUF][0] + sb), 16, 0, 0);          \
    }                                                                                      \
  } while (0)

  GSTAGE(0, 0);
  __syncthreads();
  int cur = 0;
  for (int t = 0; t < 16; ++t) {
    if (t < 15) GSTAGE(cur ^ 1, (t + 1) * 32);
    s16x8 af[4], bfr[4];
#pragma unroll
    for (int i = 0; i < 4; ++i) {
      int Ra = wm * 64 + i * 16 + l15;
      af[i] = reinterpret_cast<const s16x8*>(&As[cur][0])[Ra * 4 + (g ^ ((Ra >> 1) & 3))];
      int Rb = wn * 64 + i * 16 + l15;
      bfr[i] = reinterpret_cast<const s16x8*>(&Bs[cur][0])[Rb * 4 + (g ^ ((Rb >> 1) & 3))];
    }
#pragma unroll
    for (int mi = 0; mi < 4; ++mi)
#pragma unroll
      for (int ni = 0; ni < 4; ++ni)
        acc[mi][ni] =
            __builtin_amdgcn_mfma_f32_16x16x32_bf16(af[mi], bfr[ni], acc[mi][ni], 0, 0, 0);
    __syncthreads();
    cur ^= 1;
  }
#undef GSTAGE

  // C/D (16x16): col = lane&15, row = (lane>>4)*4 + reg
  const int rowb = tm + wm * 64 + g * 4;
  const int colb = tn + wn * 64 + l15;
#pragma unroll
  for (int mi = 0; mi < 4; ++mi) {
#pragma unroll
    for (int ni = 0; ni < 4; ++ni) {
      int r0 = rowb + mi * 16;
      int col = colb + ni * 16;
      if (EPI == 0) {
        int i3 = col >> 9, h = (col >> 6) & 7, d = col & 63;
        int b = r0 >> 12;
        int bh = b * 8 + h;
        if (i3 == 2) {  // V: 4 consecutive keys -> ushort4
          int n0 = r0 & 4095;
          int kt64 = n0 >> 6, key64 = n0 & 63;
          int kc = key64 >> 4, hk = (key64 >> 3) & 1, j0 = key64 & 7;
          int db = d >> 5, d31 = d & 31;
          ushort4 pk;
          pk.x = f2bf(acc[mi][ni][0]);
          pk.y = f2bf(acc[mi][ni][1]);
          pk.z = f2bf(acc[mi][ni][2]);
          pk.w = f2bf(acc[mi][ni][3]);
          *reinterpret_cast<ushort4*>(vt_ws + (size_t)(bh * 64 + kt64) * 4096 +
                                      ((db * 4 + kc) * 64 + d31 + 32 * hk) * 8 + j0) = pk;
        } else if (i3 == 1) {  // K: scalar x4
          int dt = d >> 4, hd = (d >> 3) & 1, j = d & 7;
#pragma unroll
          for (int r = 0; r < 4; ++r) {
            int n = (r0 + r) & 4095;
            int kt64 = n >> 6, key64 = n & 63;
            int kb = key64 >> 5, key31 = key64 & 31;
            k_ws[(size_t)(bh * 64 + kt64) * 4096 +
                 ((kb * 4 + dt) * 64 + key31 + 32 * hd) * 8 + j] = f2bf(acc[mi][ni][r]);
          }
        } else {  // Q: scalar x4, scaled
          int dt = d >> 4, hd = (d >> 3) & 1, j = d & 7;
#pragma unroll
          for (int r = 0; r < 4; ++r) {
            int n = (r0 + r) & 4095;
            int qt = n >> 5, q31 = n & 31;
            q_ws[(size_t)(bh * 128 + qt) * 2048 + (dt * 64 + q31 + 32 * hd) * 8 + j] =
                f2bf(acc[mi][ni][r] * QSCALE);
          }
        }
      } else {
#pragma unroll
        for (int r = 0; r < 4; ++r)
          outf[(size_t)(r0 + r) * 512 + col] = acc[mi][ni][r] + bias[col];
      }
    }
  }
}

// Flash attention, causal. 1024 x 256-thread (4-wave) blocks, 32x32x16 MFMA. (R18.)
// Wave = one 32-row q-tile (qt = 4G+wv). K/V tiles (8KB each) double-buffered in LDS.
// Swapped QK^T: S^T 32x32 -> lane owns query lane&31, 32 of 64 keys in regs.
// Softmax in-register; P -> PV B-frags via cvt_pk + v_permlane32_swap_b32.
// Halves h0 [0,G], h1 [G+1, ktmax]; partials (normalized bf16 + m,l) -> merge.
__global__ __launch_bounds__(256, 4) void attn_kernel(const ushort* __restrict__ Q,
                                                      const ushort* __restrict__ Kk,
                                                      const ushort* __restrict__ Vt,
                                                      ushort* __restrict__ po,
                                                      float* __restrict__ ml) {
  __shared__ ushort Ks[2][4096];
  __shared__ ushort Vs[2][4096];
  const int tid = threadIdx.x;
  const int lane = tid & 63, wv = tid >> 6;
  const int l31 = lane & 31, hf = lane >> 5;
  const int L = blockIdx.x;            // 0..1023
  const int p = L & 7;                 // XCD
  int j2 = L >> 3;                     // 0..127
  {                                    // serpentine quarters for per-CU LPT balance
    const int pos = j2 & 31, quarter = j2 >> 5;
    if (quarter & 1) j2 = quarter * 32 + (31 - pos);
  }
  const int bh = p * 2 + (j2 & 1);     // each XCD: 2 bh only
  const int i = j2 >> 1;               // 0..63
  const int G = 31 - (i >> 1);         // q-group
  const int h = i & 1;                 // kt half
  const int qt = 4 * G + wv;           // this wave's q-tile (32 rows)
  const int ktmax = qt >> 1;           // diagonal tile index
  const int mid = G + 1;
  const int klo = h ? mid : 0;
  const int khi = h ? ktmax : (mid - 1);
  const int KLO = h ? mid : 0;
  const int KHI = h ? (2 * G + 1) : (mid - 1);
  const int slot = (bh * 128 + qt) * 2 + h;
  const int qw = qt * 32;

  // Q B-frags (32x32x16): col = lane&31 = query, k = (lane>>5)*8+j = d - dt*16
  s16x8 aq[4];
  {
    const ushort* qp = Q + ((size_t)bh * 128 + qt) * 2048 + lane * 8;
#pragma unroll
    for (int dt = 0; dt < 4; ++dt) aq[dt] = *reinterpret_cast<const s16x8*>(qp + dt * 512);
  }

  f32x16 o[2] = {};  // O^T acc: db in {0,1}; col=lane&31=query, row=d
  float m = -1e30f;
  float l = 0.f;  // per-lane partial over this lane's 32 keys/tile

#define KVSTAGE(BUF, KT)                                                                  \
  do {                                                                                    \
    const ushort* kSrc = Kk + ((size_t)bh * 64 + (KT)) * 4096;                            \
    const ushort* vSrc = Vt + ((size_t)bh * 64 + (KT)) * 4096;                            \
    _Pragma("unroll") for (int c = 0; c < 2; ++c) {                                       \
      const int sb = (c * 256 + wv * 64) * 8;                                             \
      __builtin_amdgcn_global_load_lds(                                                   \
          (const __attribute__((address_space(1))) void*)(kSrc + sb + lane * 8),          \
          (__attribute__((address_space(3))) void*)(&Ks[BUF][0] + sb), 16, 0, 0);         \
      __builtin_amdgcn_global_load_lds(                                                   \
          (const __attribute__((address_space(1))) void*)(vSrc + sb + lane * 8),          \
          (__attribute__((address_space(3))) void*)(&Vs[BUF][0] + sb), 16, 0, 0);         \
    }                                                                                     \
  } while (0)

  KVSTAGE(0, KLO);
  __syncthreads();
  int cur = 0;
  for (int kt = KLO; kt <= KHI; ++kt) {
    if (kt < KHI) KVSTAGE(cur ^ 1, kt + 1);
    if (kt >= klo && kt <= khi) {
      // K A-frags: row = lane&31 = key(+32*kb), k = (lane>>5)*8+j = d - dt*16
      const ushort* kl = &Ks[cur][lane * 8];
      s16x8 kf[8];
#pragma unroll
      for (int t = 0; t < 8; ++t) kf[t] = *reinterpret_cast<const s16x8*>(kl + t * 512);
      f32x16 st[2] = {};
      __builtin_amdgcn_s_setprio(1);
#pragma unroll
      for (int kb = 0; kb < 2; ++kb)
#pragma unroll
        for (int dt = 0; dt < 4; ++dt)
          st[kb] = __builtin_amdgcn_mfma_f32_32x32x16_bf16(kf[kb * 4 + dt], aq[dt],
                                                           st[kb], 0, 0, 0);
      __builtin_amdgcn_s_setprio(0);
      // C/D 32x32: col = lane&31 = query, row = (r&3)+8*(r>>2)+4*(lane>>5) = key(+32kb)
      if (kt == ktmax) {  // diagonal: mask key > query
        const int qg = qw + l31;
#pragma unroll
        for (int kb = 0; kb < 2; ++kb)
#pragma unroll
          for (int r = 0; r < 16; ++r)
            if (kt * 64 + kb * 32 + (r & 3) + 8 * (r >> 2) + 4 * hf > qg)
              st[kb][r] = -1e30f;
      }
      // lane-local max over this lane's 32 keys
      float mx[2];
#pragma unroll
      for (int kb = 0; kb < 2; ++kb) {
        float t0 = fmaxf(fmaxf(st[kb][0], st[kb][1]), fmaxf(st[kb][2], st[kb][3]));
        float t1 = fmaxf(fmaxf(st[kb][4], st[kb][5]), fmaxf(st[kb][6], st[kb][7]));
        float t2 = fmaxf(fmaxf(st[kb][8], st[kb][9]), fmaxf(st[kb][10], st[kb][11]));
        float t3 = fmaxf(fmaxf(st[kb][12], st[kb][13]), fmaxf(st[kb][14], st[kb][15]));
        mx[kb] = fmaxf(fmaxf(t0, t1), fmaxf(t2, t3));
      }
      float pm = fmaxf(mx[0], mx[1]);
      if (!__all(pm - m <= 8.0f)) {  // rare: joint (pair) max + rescale
        float pmf = fmaxf(pm, __shfl_xor(pm, 32));
        const float mn = fmaxf(m, pmf);
        const float al = __builtin_amdgcn_exp2f(m - mn);
        l *= al;
        m = mn;
#pragma unroll
        for (int db = 0; db < 2; ++db)
#pragma unroll
          for (int r = 0; r < 16; ++r) o[db][r] *= al;
      }
      // exp + pack into PV B-frags: pb[kc] k-elems = kc*16 + (lane>>5)*8 + j
      s16x8 pb[4];
      float rs = 0.f;
#pragma unroll
      for (int kb = 0; kb < 2; ++kb) {
        float e[16];
#pragma unroll
        for (int r = 0; r < 16; ++r) {
          e[r] = __builtin_amdgcn_exp2f(st[kb][r] - m);
          rs += e[r];
        }
        unsigned a0 = cvt_pk_bf16(e[0], e[1]), a1 = cvt_pk_bf16(e[2], e[3]);
        unsigned b0 = cvt_pk_bf16(e[4], e[5]), b1 = cvt_pk_bf16(e[6], e[7]);
        asm volatile("v_permlane32_swap_b32 %0, %1" : "+v"(a0), "+v"(b0));
        asm volatile("v_permlane32_swap_b32 %0, %1" : "+v"(a1), "+v"(b1));
        u32x4 w0;
        w0[0] = a0; w0[1] = a1; w0[2] = b0; w0[3] = b1;
        pb[kb * 2] = __builtin_bit_cast(s16x8, w0);
        unsigned c0 = cvt_pk_bf16(e[8], e[9]), c1 = cvt_pk_bf16(e[10], e[11]);
        unsigned d0 = cvt_pk_bf16(e[12], e[13]), d1 = cvt_pk_bf16(e[14], e[15]);
        asm volatile("v_permlane32_swap_b32 %0, %1" : "+v"(c0), "+v"(d0));
        asm volatile("v_permlane32_swap_b32 %0, %1" : "+v"(c1), "+v"(d1));
        u32x4 w1;
        w1[0] = c0; w1[1] = c1; w1[2] = d0; w1[3] = d1;
        pb[kb * 2 + 1] = __builtin_bit_cast(s16x8, w1);
      }
      l += rs;
      // V A-frags: row = lane&31 = d(+32*db), k = (lane>>5)*8+j = key - kc*16
      const ushort* vl = &Vs[cur][lane * 8];
      s16x8 vf[8];
#pragma unroll
      for (int t = 0; t < 8; ++t) vf[t] = *reinterpret_cast<const s16x8*>(vl + t * 512);
      __builtin_amdgcn_s_setprio(1);
#pragma unroll
      for (int db = 0; db < 2; ++db)
#pragma unroll
        for (int kc = 0; kc < 4; ++kc)
          o[db] = __builtin_amdgcn_mfma_f32_32x32x16_bf16(vf[db * 4 + kc], pb[kc],
                                                          o[db], 0, 0, 0);
      __builtin_amdgcn_s_setprio(0);
    }
    __syncthreads();  // drains staged loads + LDS reads; buffers safe to swap
    cur ^= 1;
  }
#undef KVSTAGE

  // l: pair-reduce (lane, lane+32) covers the full 64-key rows
  float lr = l + __shfl_xor(l, 32);
  const float linv = (lr > 0.f) ? (1.0f / lr) : 0.f;

  // Partial O: row = query = lane&31; o[db] reg r -> d = db*32 + 8*(r>>2) + 4*hf + (r&3)
  const size_t pbase = ((size_t)slot * 32 + l31) * 64;
#pragma unroll
  for (int db = 0; db < 2; ++db)
#pragma unroll
    for (int rg = 0; rg < 4; ++rg) {
      const int d0 = db * 32 + 8 * rg + 4 * hf;
      uint2 pk;
      pk.x = cvt_pk_bf16(o[db][rg * 4 + 0] * linv, o[db][rg * 4 + 1] * linv);
      pk.y = cvt_pk_bf16(o[db][rg * 4 + 2] * linv, o[db][rg * 4 + 3] * linv);
      *reinterpret_cast<uint2*>(po + pbase + d0) = pk;
    }
  if (hf == 0) {
    float2 v;
    v.x = m;
    v.y = lr;
    *reinterpret_cast<float2*>(ml + ((size_t)slot * 32 + l31) * 2) = v;
  }
}

// Merge the two KV-halves of every q-tile. 2048 blocks x 64 threads.
__global__ __launch_bounds__(64) void attn_merge(const ushort* __restrict__ po,
                                                 const float* __restrict__ ml,
                                                 ushort* __restrict__ O) {
  const int M = blockIdx.x, tid = threadIdx.x;
  const int p = M & 7, q2 = M >> 3;   // q2 0..255
  const int bh = p * 2 + (q2 & 1);
  const int qt = q2 >> 1;             // 0..127
  const int t = bh * 128 + qt;
  const int row = tid >> 1, dh = (tid & 1) * 32;
  const float2 ml0 = *reinterpret_cast<const float2*>(ml + ((size_t)(t * 2 + 0) * 32 + row) * 2);
  const float2 ml1 = *reinterpret_cast<const float2*>(ml + ((size_t)(t * 2 + 1) * 32 + row) * 2);
  const float ms = fmaxf(ml0.x, ml1.x);
  const float w0 = __builtin_amdgcn_exp2f(ml0.x - ms) * ml0.y;
  const float w1 = __builtin_amdgcn_exp2f(ml1.x - ms) * ml1.y;
  const float inv = 1.0f / (w0 + w1);
  const float c0 = w0 * inv, c1 = w1 * inv;
  const int b = bh >> 3, h = bh & 7;
  const size_t rowo = (size_t)(b * 4096 + qt * 32 + row) * 512 + h * 64 + dh;
  const ushort* p0 = po + ((size_t)(t * 2 + 0) * 32 + row) * 64 + dh;
  const ushort* p1 = po + ((size_t)(t * 2 + 1) * 32 + row) * 64 + dh;
#pragma unroll
  for (int j = 0; j < 4; ++j) {
    uint4 a = reinterpret_cast<const uint4*>(p0)[j];
    uint4 bb = reinterpret_cast<const uint4*>(p1)[j];
    uint4 out;
    out.x = cvt_pk_bf16(c0 * bflo(a.x) + c1 * bflo(bb.x), c0 * bfhi(a.x) + c1 * bfhi(bb.x));
    out.y = cvt_pk_bf16(c0 * bflo(a.y) + c1 * bflo(bb.y), c0 * bfhi(a.y) + c1 * bfhi(bb.y));
    out.z = cvt_pk_bf16(c0 * bflo(a.z) + c1 * bflo(bb.z), c0 * bfhi(a.z) + c1 * bfhi(bb.z));
    out.w = cvt_pk_bf16(c0 * bflo(a.w) + c1 * bflo(bb.w), c0 * bfhi(a.w) + c1 * bfhi(bb.w));
    reinterpret_cast<uint4*>(&O[rowo])[j] = out;
  }
}

extern "C" void kernel_launch(void* const* d_in, const int* in_sizes, int n_in,
                              void* d_out, int out_size, void* d_ws, size_t ws_size,
                              hipStream_t stream) {
  const float* x = (const float*)d_in[0];       // [2,4096,512]
  const float* w_qkv = (const float*)d_in[1];   // [1536,512]
  const float* w_proj = (const float*)d_in[2];  // [512,512]
  const float* b_proj = (const float*)d_in[3];  // [512]
  float* out = (float*)d_out;                   // [2,4096,512]

  ushort* xb = (ushort*)d_ws;                       // 8192*512
  ushort* wqkvb = xb + (size_t)8192 * 512;          // 1536*512
  ushort* wprojb = wqkvb + (size_t)1536 * 512;      // 512*512
  ushort* qws = wprojb + (size_t)512 * 512;         // 16*128*2048
  ushort* kws = qws + (size_t)16 * 4096 * 64;       // 16*64*4096
  ushort* vtws = kws + (size_t)16 * 4096 * 64;
  ushort* ows = vtws + (size_t)16 * 4096 * 64;      // 8192*512

  cvt_all<<<5120, 256, 0, stream>>>(x, w_qkv, w_proj, xb, wqkvb, wprojb);

  // QKV GEMM: M=8192 (64 tiles), N=1536 (12 tiles) -> 768 blocks, XCD-swizzled 1-D.
  gemm_bt<0, 12><<<768, 256, 0, stream>>>(xb, wqkvb, qws, kws, vtws, nullptr, nullptr);

  // Partials at ws tail (R14 verified ws >= 70.8MB).
  ushort* po = ows + (size_t)8192 * 512;
  float* ml = (float*)(po + (size_t)2048 * 2 * 32 * 64);

  attn_kernel<<<1024, 256, 0, stream>>>(qws, kws, vtws, po, ml);
  attn_merge<<<2048, 64, 0, stream>>>(po, ml, ows);

  // Proj GEMM: M=8192 (64 tiles), N=512 (4 tiles) -> 256 blocks, XCD-swizzled 1-D.
  gemm_bt<1, 4><<<256, 256, 0, stream>>>(ows, wprojb, nullptr, nullptr, nullptr, out,
                                         b_proj);
}